// Round 11
// baseline (1726.284 us; speedup 1.0000x reference)
//
#include <hip/hip_runtime.h>

#define B_ 128
#define T_ 256
#define IN_ 256
#define H_ 512
#define G4_ 2048   // 4*H
#define TC_ 16     // time chunk (scan/L1)
#define NCHUNK_ 16

typedef __attribute__((ext_vector_type(8))) short short8v;   // 8 bf16
typedef __attribute__((ext_vector_type(4))) float float4v;

// ---- workspace layout (float offsets) ---- (~61MB total)
static constexpr size_t OFF_XG0 = 0;                                  // B*32*4H fp32 (2 chunks)
static constexpr size_t OFF_XG1 = OFF_XG0 + (size_t)B_ * 32 * G4_;    // B*16*4H fp32
static constexpr size_t OFF_H0C = OFF_XG1 + (size_t)B_ * TC_ * G4_;   // B*TC*H bf16
static constexpr size_t OFF_HB0 = OFF_H0C + (size_t)B_ * TC_ * H_ / 2;// 2 slots B*H bf16
static constexpr size_t OFF_HB1 = OFF_HB0 + (size_t)B_ * H_;
static constexpr size_t OFF_C0  = OFF_HB1 + (size_t)B_ * H_;          // B*H fp32
static constexpr size_t OFF_C1  = OFF_C0 + (size_t)B_ * H_;
static constexpr size_t OFF_WF0 = OFF_C1 + (size_t)B_ * H_;           // W_hh0 bf16 frags
static constexpr size_t OFF_WF1 = OFF_WF0 + (size_t)G4_ * H_ / 2;
static constexpr size_t OFF_WI0 = OFF_WF1 + (size_t)G4_ * H_ / 2;     // W_ih0 frags (K=256)
static constexpr size_t OFF_WI1 = OFF_WI0 + (size_t)G4_ * IN_ / 2;    // W_ih1 frags (K=512)
static constexpr size_t OFF_END = OFF_WI1 + (size_t)G4_ * H_ / 2;     // 15,204,352 floats

// bf16 round-to-nearest-even from fp32
__device__ __forceinline__ unsigned int bfr(float f) {
  unsigned int u = __float_as_uint(f);
  return (u + 0x7fffu + ((u >> 16) & 1u)) >> 16;
}
#define BLO(u) __uint_as_float((u) << 16)
#define BHI(u) __uint_as_float((u) & 0xffff0000u)

// ============================================================================
// Pack W_hh [2048][512] fp32 -> bf16 MFMA B-fragments, gate-tiled order
// (ct,g,ks): lane l holds W[g*512+ct*16+(l&15)][ks*32+(l>>4)*8 .. +7].
// ============================================================================
__global__ __launch_bounds__(256) void pack_whh3(
    const float* __restrict__ W, uint4* __restrict__ WF) {
  const int idx = blockIdx.x * 256 + threadIdx.x;  // 0..131071
  const int l  = idx & 63;
  const int ks = (idx >> 6) & 15;
  const int g  = (idx >> 10) & 3;
  const int ct = idx >> 12;                        // 0..31
  const int row = g * H_ + ct * 16 + (l & 15);
  const int k0  = ks * 32 + (l >> 4) * 8;
  const float* s = W + (size_t)row * H_ + k0;
  uint4 o;
  o.x = bfr(s[0]) | (bfr(s[1]) << 16);
  o.y = bfr(s[2]) | (bfr(s[3]) << 16);
  o.z = bfr(s[4]) | (bfr(s[5]) << 16);
  o.w = bfr(s[6]) | (bfr(s[7]) << 16);
  WF[idx] = o;
}

// ============================================================================
// Pack W_ih [2048][K] fp32 -> bf16 MFMA B-fragments, plain n-tile order:
// frag (nt, ks): lane l holds W[nt*16+(l&15)][ks*32+(l>>4)*8 .. +7].
// ============================================================================
__global__ __launch_bounds__(256) void pack_wih(
    const float* __restrict__ W, uint4* __restrict__ WF, int K) {
  const int idx = blockIdx.x * 256 + threadIdx.x;
  const int ksn = K >> 5;
  const int l  = idx & 63;
  const int ks = (idx >> 6) & (ksn - 1);
  const int nt = idx >> 6 >> (K == 512 ? 4 : 3);
  const int row = nt * 16 + (l & 15);
  const int k0  = ks * 32 + (l >> 4) * 8;
  const float* s = W + (size_t)row * K + k0;
  uint4 o;
  o.x = bfr(s[0]) | (bfr(s[1]) << 16);
  o.y = bfr(s[2]) | (bfr(s[3]) << 16);
  o.z = bfr(s[4]) | (bfr(s[5]) << 16);
  o.w = bfr(s[6]) | (bfr(s[7]) << 16);
  WF[idx] = o;
}

// ============================================================================
// MFMA GEMM: C[m][n] = sum_k A(m)[k]*W[n][k] + b1[n]+b2[n]. C fp32 [G4].
// A row(m) = (m>>tcl)*T_A + t0 + (m & ((1<<tcl)-1)); A fp32 (abf=0, converted
// to bf16 during staging) or bf16 (abf=1). Grid = 8*(M/64)*(N/512) blocks,
// XCD-clustered B-slices (L2-resident). Block 64x64, 4 waves.
// ============================================================================
__global__ __launch_bounds__(256) void gemm_xg_mfma(
    const void* __restrict__ Av, const short8v* __restrict__ WF,
    const float* __restrict__ bias1, const float* __restrict__ bias2,
    float* __restrict__ C, int K, int T_A, int t0, int tcl, int abf) {
  __shared__ uint4 Ash[64 * 64];       // 64KB max (uses 64*(K/8))
  const int bid = blockIdx.x;
  const int xcd = bid & 7;
  const int q   = bid >> 3;
  const int n0  = (xcd * 4 + (q & 3)) * 64;
  const int m0  = (q >> 2) * 64;
  const int tid = threadIdx.x;
  const int ch  = K >> 3;              // uint4 chunks per row (32 or 64)
  const int chl = (K == 512) ? 6 : 5;
  const int ksn = K >> 5;
  const int tcm = (1 << tcl) - 1;

  const int total = 64 << chl;
  for (int idx = tid; idx < total; idx += 256) {
    const int r = idx >> chl, c = idx & (ch - 1);
    const int m = m0 + r;
    const size_t arow = (size_t)(m >> tcl) * T_A + t0 + (m & tcm);
    uint4 val;
    if (abf) {
      val = *(const uint4*)((const unsigned short*)Av + arow * K + c * 8);
    } else {
      const float* ap = (const float*)Av + arow * K + c * 8;
      const float4 lo = *(const float4*)ap;
      const float4 hi = *(const float4*)(ap + 4);
      val.x = bfr(lo.x) | (bfr(lo.y) << 16);
      val.y = bfr(lo.z) | (bfr(lo.w) << 16);
      val.z = bfr(hi.x) | (bfr(hi.y) << 16);
      val.w = bfr(hi.z) | (bfr(hi.w) << 16);
    }
    Ash[(r << chl) + (c ^ (r & 7))] = val;
  }
  __syncthreads();

  const int lane = tid & 63;
  const int w = tid >> 6;              // wave = 16-col slice
  const int ar = lane & 15;
  const int koct = lane >> 4;
  const int nt = (n0 >> 4) + w;
  const short8v* wf = WF + (size_t)nt * ksn * 64 + lane;
  float4v acc0 = {0,0,0,0}, acc1 = {0,0,0,0}, acc2 = {0,0,0,0}, acc3 = {0,0,0,0};
#pragma unroll 4
  for (int ks = 0; ks < ksn; ++ks) {
    const short8v bv = wf[(size_t)ks * 64];
    const int cc = ks * 4 + koct;
    const short8v a0 = *(const short8v*)&Ash[((ar +  0) << chl) + (cc ^ ((ar +  0) & 7))];
    const short8v a1 = *(const short8v*)&Ash[((ar + 16) << chl) + (cc ^ ((ar + 16) & 7))];
    const short8v a2 = *(const short8v*)&Ash[((ar + 32) << chl) + (cc ^ ((ar + 32) & 7))];
    const short8v a3 = *(const short8v*)&Ash[((ar + 48) << chl) + (cc ^ ((ar + 48) & 7))];
    acc0 = __builtin_amdgcn_mfma_f32_16x16x32_bf16(a0, bv, acc0, 0, 0, 0);
    acc1 = __builtin_amdgcn_mfma_f32_16x16x32_bf16(a1, bv, acc1, 0, 0, 0);
    acc2 = __builtin_amdgcn_mfma_f32_16x16x32_bf16(a2, bv, acc2, 0, 0, 0);
    acc3 = __builtin_amdgcn_mfma_f32_16x16x32_bf16(a3, bv, acc3, 0, 0, 0);
  }
  const int dcol = lane & 15, drow = (lane >> 4) * 4;
  const int n = n0 + w * 16 + dcol;
  const float bs = bias1[n] + bias2[n];
  float* Cb = C + (size_t)(m0 + drow) * G4_ + n;
#pragma unroll
  for (int rr = 0; rr < 4; ++rr) {
    Cb[(size_t)(0 + rr) * G4_]  = acc0[rr] + bs;
    Cb[(size_t)(16 + rr) * G4_] = acc1[rr] + bs;
    Cb[(size_t)(32 + rr) * G4_] = acc2[rr] + bs;
    Cb[(size_t)(48 + rr) * G4_] = acc3[rr] + bs;
  }
}

// ============================================================================
// Fused 2-layer MFMA LSTM step — 8-wave, weight-register-preload variant.
// mode 0: 512 blocks (L0+L1); 1: 256 L0; 2: 256 L1. 512 threads / 8 waves.
// Wave (g, kh): preloads its 8 B-fragments into VGPRs FIRST (LLC latency
// overlaps xg/c prefetch + h staging + barrier), then 8 pure-LDS MFMAs.
// L0 xg stride 32 (merged 2-chunk XG0, index tl0); L1 stride 16 (tl1).
// ============================================================================
__global__ __launch_bounds__(512) void lstm_step2(
    const short8v* __restrict__ WF0, const float* __restrict__ xg0,
    const unsigned short* __restrict__ h0p, unsigned short* __restrict__ h0n,
    float* __restrict__ cs0, unsigned short* __restrict__ h0c,
    const short8v* __restrict__ WF1, const float* __restrict__ xg1,
    const unsigned short* __restrict__ h1p, unsigned short* __restrict__ h1n,
    float* __restrict__ cs1, int tl0, int tl1, int mode) {
  __shared__ unsigned short hsh[16 * 512];  // 16KB h tile (bf16, chunk-swizzled)
  __shared__ float gl[2][4][16][17];        // gate tiles per k-half
  const int bid = blockIdx.x;
  const int layer = (mode == 0) ? (bid >> 8) : (mode - 1);
  const int xcd = bid & 7;
  const int ctl = (bid >> 3) & 3;
  const int bt  = (bid >> 5) & 7;
  const int ct  = xcd * 4 + ctl;
  const int b0  = bt * 16;

  const short8v* WF; const float* xg; const unsigned short* hprev;
  unsigned short* hnext; float* cst;
  int xtl, xsl;
  if (layer == 0) { WF = WF0; xg = xg0; hprev = h0p; hnext = h0n; cst = cs0;
                    xtl = tl0; xsl = 5; }
  else            { WF = WF1; xg = xg1; hprev = h1p; hnext = h1n; cst = cs1;
                    xtl = tl1; xsl = 4; }

  const int tid = threadIdx.x;
  const int lane = tid & 63;
  const int w = tid >> 6;
  const int g = w >> 1;
  const int kh = w & 1;

  // ---- issue weight loads FIRST: latency hides under prefetch+staging ----
  const short8v* wf = WF + ((size_t)(ct * 4 + g) * 16) * 64 + lane;
  short8v wreg[8];
#pragma unroll
  for (int i = 0; i < 8; ++i) wreg[i] = wf[(size_t)(kh * 8 + i) * 64];

  // tail identity + xg/c prefetch (threads 0..255 only)
  const int tb = tid >> 4, thc = tid & 15;
  float xi = 0.f, xf = 0.f, xgv = 0.f, xo = 0.f, cin = 0.f;
  int bb = 0, hcol = 0;
  if (tid < 256) {
    bb = b0 + tb;
    hcol = ct * 16 + thc;
    const float* xr = xg + (((size_t)bb << xsl) + xtl) * G4_ + hcol;
    xi = xr[0]; xf = xr[512]; xgv = xr[1024]; xo = xr[1536];
    cin = cst[(size_t)bb * H_ + hcol];
  }

  // stage h tile: 16 rows x 64 chunks(16B bf16x8), swizzle chunk c -> c^(r&7)
  const uint4* hp4 = (const uint4*)hprev + (size_t)b0 * 64;
#pragma unroll
  for (int j = 0; j < 2; ++j) {
    const int idx = tid + j * 512;
    const int r = idx >> 6, c = idx & 63;
    *(uint4*)&hsh[(r * 64 + (c ^ (r & 7))) * 8] = hp4[(size_t)r * 64 + c];
  }
  __syncthreads();

  // MFMA: pure LDS + preloaded weights
  const int ar = lane & 15;
  const int koct = lane >> 4;
  float4v acc = {0.f, 0.f, 0.f, 0.f};
#pragma unroll
  for (int ksl = 0; ksl < 8; ++ksl) {
    const int c16 = (kh * 8 + ksl) * 4 + koct;
    const short8v av = *(const short8v*)&hsh[(ar * 64 + (c16 ^ (ar & 7))) * 8];
    acc = __builtin_amdgcn_mfma_f32_16x16x32_bf16(av, wreg[ksl], acc, 0, 0, 0);
  }
  // D layout: col = lane&15, row = (lane>>4)*4 + reg
  const int drow = (lane >> 4) * 4, dcol = lane & 15;
#pragma unroll
  for (int rr = 0; rr < 4; ++rr) gl[kh][g][drow + rr][dcol] = acc[rr];
  __syncthreads();

  // tail: threads 0..255 combine k-halves + 4 gates
  if (tid < 256) {
    const float gi = gl[0][0][tb][thc] + gl[1][0][tb][thc] + xi;
    const float gf = gl[0][1][tb][thc] + gl[1][1][tb][thc] + xf;
    const float gg = gl[0][2][tb][thc] + gl[1][2][tb][thc] + xgv;
    const float go = gl[0][3][tb][thc] + gl[1][3][tb][thc] + xo;
    const float iv = 1.f / (1.f + __expf(-gi));
    const float fv = 1.f / (1.f + __expf(-gf));
    const float gv = tanhf(gg);
    const float ov = 1.f / (1.f + __expf(-go));
    const float cn = fv * cin + iv * gv;
    const float hv = ov * tanhf(cn);
    cst[(size_t)bb * H_ + hcol] = cn;
    const unsigned short hb = (unsigned short)bfr(hv);
    hnext[(size_t)bb * H_ + hcol] = hb;
    if (layer == 0) h0c[((size_t)bb * TC_ + tl1) * H_ + hcol] = hb;
  }
}

// ============================================================================
// Final FC (10 classes) + log_softmax. One wave per batch row; h is bf16.
// ============================================================================
__global__ __launch_bounds__(64) void fc_logsoftmax(
    const unsigned short* __restrict__ h, const float* __restrict__ Wfc,
    const float* __restrict__ bfc, float* __restrict__ out) {
  const int b = blockIdx.x, lane = threadIdx.x;
  const uint4 hv = *(const uint4*)(h + (size_t)b * H_ + lane * 8);
  const float hf[8] = {BLO(hv.x), BHI(hv.x), BLO(hv.y), BHI(hv.y),
                       BLO(hv.z), BHI(hv.z), BLO(hv.w), BHI(hv.w)};
  float logits[10];
#pragma unroll
  for (int cc = 0; cc < 10; ++cc) {
    const float* wr = Wfc + (size_t)cc * H_ + lane * 8;
    const float4 w0 = *(const float4*)wr;
    const float4 w1 = *(const float4*)(wr + 4);
    float v = hf[0] * w0.x + hf[1] * w0.y + hf[2] * w0.z + hf[3] * w0.w +
              hf[4] * w1.x + hf[5] * w1.y + hf[6] * w1.z + hf[7] * w1.w;
#pragma unroll
    for (int off = 32; off; off >>= 1) v += __shfl_xor(v, off);
    logits[cc] = v + bfc[cc];
  }
  float m = logits[0];
#pragma unroll
  for (int cc = 1; cc < 10; ++cc) m = fmaxf(m, logits[cc]);
  float s = 0.f;
#pragma unroll
  for (int cc = 0; cc < 10; ++cc) s += __expf(logits[cc] - m);
  const float lse = m + __logf(s);
  if (lane < 10) out[(size_t)b * 10 + lane] = logits[lane] - lse;
}

// ============================================================================
extern "C" void kernel_launch(void* const* d_in, const int* in_sizes, int n_in,
                              void* d_out, int out_size, void* d_ws, size_t ws_size,
                              hipStream_t stream) {
  const float* x    = (const float*)d_in[0];
  const float* Wih0 = (const float*)d_in[1];
  const float* Whh0 = (const float*)d_in[2];
  const float* bih0 = (const float*)d_in[3];
  const float* bhh0 = (const float*)d_in[4];
  const float* Wih1 = (const float*)d_in[5];
  const float* Whh1 = (const float*)d_in[6];
  const float* bih1 = (const float*)d_in[7];
  const float* bhh1 = (const float*)d_in[8];
  const float* Wfc  = (const float*)d_in[9];
  const float* bfc  = (const float*)d_in[10];

  float* ws   = (float*)d_ws;
  float* XG0  = ws + OFF_XG0;
  float* XG1  = ws + OFF_XG1;
  unsigned short* h0c = (unsigned short*)(ws + OFF_H0C);
  unsigned short* hb0 = (unsigned short*)(ws + OFF_HB0);
  unsigned short* hb1 = (unsigned short*)(ws + OFF_HB1);
  float* c0   = ws + OFF_C0;
  float* c1   = ws + OFF_C1;
  short8v* wf0 = (short8v*)(ws + OFF_WF0);
  short8v* wf1 = (short8v*)(ws + OFF_WF1);
  short8v* wi0 = (short8v*)(ws + OFF_WI0);
  short8v* wi1 = (short8v*)(ws + OFF_WI1);

  // zero h ping-pongs + c states; pack weights to MFMA fragments
  hipMemsetAsync(hb0, 0, (OFF_WF0 - OFF_HB0) * sizeof(float), stream);
  pack_whh3<<<512, 256, 0, stream>>>(Whh0, (uint4*)wf0);
  pack_whh3<<<512, 256, 0, stream>>>(Whh1, (uint4*)wf1);
  pack_wih<<<256, 256, 0, stream>>>(Wih0, (uint4*)wi0, IN_);
  pack_wih<<<512, 256, 0, stream>>>(Wih1, (uint4*)wi1, H_);

  const size_t BHu = (size_t)B_ * H_;  // bf16 slot stride
  for (int ch = 0; ch < NCHUNK_; ++ch) {
    const int t0 = ch * TC_;
    if ((ch & 1) == 0)  // L0 input gates for 2 chunks (32 steps), x fp32->bf16 inline
      gemm_xg_mfma<<<2048, 256, 0, stream>>>(x, wi0, bih0, bhh0, XG0,
                                             IN_, T_, t0, 5, 0);
    if (ch > 0)         // L1 input gates from prev chunk's bf16 h0
      gemm_xg_mfma<<<1024, 256, 0, stream>>>(h0c, wi1, bih1, bhh1, XG1,
                                             H_, TC_, 0, 4, 1);
    for (int t = 0; t < TC_; ++t) {
      const int sg0 = t0 + t + 1;        // L0 global step (1-based)
      const int sg1 = sg0 - TC_;         // L1 global step (prev chunk)
      const int mode = (ch == 0) ? 1 : 0;
      const int nblk = (ch == 0) ? 256 : 512;
      lstm_step2<<<nblk, 512, 0, stream>>>(
          wf0, XG0, hb0 + ((sg0 - 1) & 1) * BHu, hb0 + (sg0 & 1) * BHu, c0, h0c,
          wf1, XG1, hb1 + ((sg1 - 1) & 1) * BHu, hb1 + (sg1 & 1) * BHu, c1,
          (t0 + t) & 31, t, mode);
    }
  }
  // pipeline drain: L1 over the last chunk
  gemm_xg_mfma<<<1024, 256, 0, stream>>>(h0c, wi1, bih1, bhh1, XG1,
                                         H_, TC_, 0, 4, 1);
  for (int t = 0; t < TC_; ++t) {
    const int sg1 = (NCHUNK_ - 1) * TC_ + t + 1;
    lstm_step2<<<256, 512, 0, stream>>>(
        wf0, XG0, hb0, hb0, c0, h0c,
        wf1, XG1, hb1 + ((sg1 - 1) & 1) * BHu, hb1 + (sg1 & 1) * BHu, c1,
        0, t, 2);
  }
  // T=256 even -> final h1 in bf16 slot 0
  fc_logsoftmax<<<dim3(B_), 64, 0, stream>>>(hb1, Wfc, bfc, (float*)d_out);
}